// Round 17
// baseline (251.837 us; speedup 1.0000x reference)
//
#include <hip/hip_runtime.h>

#define NT   256
#define IMG  512
#define BT   64     // block output tile: 64x64 (4 waves x 4 rt-quadrants)
#define RAWR 74     // staged rows: 64+10 halo; rows 74..79 have zero V-weight
#define RAWU 44     // raw row stride in uints (40 data + 4 pad)

typedef _Float16 f16x8 __attribute__((ext_vector_type(8)));
typedef _Float16 f16x4 __attribute__((ext_vector_type(4)));
typedef float    f32x4 __attribute__((ext_vector_type(4)));

__device__ inline unsigned pk2(float a, float b) {
    auto r = __builtin_amdgcn_cvt_pkrtz(a, b);     // f32x2 -> f16x2 (RTZ)
    return __builtin_bit_cast(unsigned, r);
}

// ---------------------------------------------------------------------------
// SSIM via MFMA, v11 = v10 (35.8 us) fused to a SINGLE dispatch:
//  - band fragments computed in-block (same arithmetic as the old init
//    kernel -> bit-identical; at 4096 blocks it's ~1.5% of block lifetime,
//    cheaper than a serialized launch+gap).
//  - final reduction folded in via last-block-done: device-scope (agent)
//    release store of each partial + acquire loads in the last block
//    (required across non-coherent XCD L2s); the summation order is FIXED
//    (thread i: partial[i], partial[i+256], ...) so the output is
//    deterministic regardless of which block runs it. Counter zeroed by
//    hipMemsetAsync in kernel_launch (graph-safe, replayed per call).
// Compute structure unchanged from v10:
//   H-conv:  H[m][16ct+n] = sum_k raw[m][16ct+k] * B1[k][n], B1[k][n]=w[k-n-3]
//   V-conv:  out[16rt+r][n] = sum_j w[j-r] * H[16rt+j][n] (two chained K=16
//            MFMAs; C-layout of K=32 MFMA == B-layout of K=16 MFMA)
//   PP/TT/PT A-frags derived in-register as products of P/T frags.
//   74 staged rows; mt=4 lm>=10 clamps to row 73 (zero V-weight, bit-exact).
// launch_bounds(256,4): round 4 showed tighter caps spill to scratch.
// ---------------------------------------------------------------------------
__global__ __launch_bounds__(NT, 4) void ssim_mfma_kernel(
    const float* __restrict__ pred,
    const float* __restrict__ target,
    const float* __restrict__ kern,
    float* __restrict__ partial,
    unsigned* __restrict__ counter,
    float* __restrict__ out,
    int nblocks, float inv_npix)
{
    __shared__ __align__(16) unsigned sRaw[2][RAWR][RAWU];   // 25.4 KB
    __shared__ float sRed[4];
    __shared__ int   sLast;

    const int tid = threadIdx.x;

    // ---- bijective XCD swizzle (gridDim.x % 8 == 0) ----
    const int bid   = blockIdx.x;
    const int chunk = (int)gridDim.x >> 3;
    const int swz   = (bid & 7) * chunk + (bid >> 3);
    const int img   = swz >> 6;               // 64 tiles per image
    const int rem   = swz & 63;
    const int tx0   = (rem & 7) * BT;
    const int ty0   = (rem >> 3) * BT;

    const int lane = tid & 63;
    const int wv   = tid >> 6;
    const int lm   = lane & 15;     // m (A row) / n (B col) / C col
    const int lg   = lane >> 4;     // k-group; C row-group

    // ---- band fragments in-block (identical arithmetic to old init kernel) ----
    const float invg = 1.0f / sqrtf(kern[60]);
    auto wof = [&](int i) -> float {
        return ((unsigned)i <= 10u) ? kern[55 + i] * invg : 0.0f;
    };
    unsigned bu[4], au[4];
    #pragma unroll
    for (int jp = 0; jp < 4; ++jp) {
        const int d = 8 * lg + 2 * jp - lm - 3;    // K=32 B1 band: w[k-n-3]
        bu[jp] = pk2(wof(d), wof(d + 1));
    }
    #pragma unroll
    for (int jp = 0; jp < 2; ++jp) {
        const int e = 4 * lg + 2 * jp - lm;        // K=16 A2 band: w[k-r]
        au[jp]     = pk2(wof(e),      wof(e + 1));
        au[2 + jp] = pk2(wof(e + 16), wof(e + 17));
    }
    const f16x8 bfrag = __builtin_bit_cast(f16x8, make_uint4(bu[0], bu[1], bu[2], bu[3]));
    const f16x4 a2k0  = __builtin_bit_cast(f16x4, make_uint2(au[0], au[1]));
    const f16x4 a2k1  = __builtin_bit_cast(f16x4, make_uint2(au[2], au[3]));
    const f32x4 zero4 = {0.f, 0.f, 0.f, 0.f};

    // ---- stage raw P,T (f16): 74 rows x 10 groups of 8 px ----
    {
        const float* pimg = pred   + (size_t)img * (IMG * IMG);
        const float* timg = target + (size_t)img * (IMG * IMG);
        if ((unsigned)(tx0 - 64) <= 320u && (unsigned)(ty0 - 64) <= 320u) {
            #pragma unroll
            for (int i = tid; i < RAWR * 10; i += NT) {
                const int r  = i / 10;
                const int cg = i - r * 10;
                const float* prow = pimg + (ty0 - 5 + r) * IMG + (tx0 - 8 + 8 * cg);
                const float* trow = timg + (ty0 - 5 + r) * IMG + (tx0 - 8 + 8 * cg);
                const float4 p0 = *(const float4*)(prow);
                const float4 p1 = *(const float4*)(prow + 4);
                const float4 t0 = *(const float4*)(trow);
                const float4 t1 = *(const float4*)(trow + 4);
                const int u = 4 * cg;
                *(uint4*)&sRaw[0][r][u] = make_uint4(pk2(p0.x, p0.y), pk2(p0.z, p0.w),
                                                     pk2(p1.x, p1.y), pk2(p1.z, p1.w));
                *(uint4*)&sRaw[1][r][u] = make_uint4(pk2(t0.x, t0.y), pk2(t0.z, t0.w),
                                                     pk2(t1.x, t1.y), pk2(t1.z, t1.w));
            }
        } else {
            for (int i = tid; i < RAWR * 10; i += NT) {
                const int r  = i / 10;
                const int cg = i - r * 10;
                const int gy = ty0 - 5 + r;
                const int gx = tx0 - 8 + 8 * cg;     // multiple of 4
                float4 p0 = make_float4(0.f, 0.f, 0.f, 0.f), p1 = p0, t0 = p0, t1 = p0;
                if ((unsigned)gy < IMG) {
                    const float* prow = pimg + gy * IMG;
                    const float* trow = timg + gy * IMG;
                    if ((unsigned)gx < IMG) {
                        p0 = *(const float4*)(prow + gx);
                        t0 = *(const float4*)(trow + gx);
                    }
                    if ((unsigned)(gx + 4) < IMG) {
                        p1 = *(const float4*)(prow + gx + 4);
                        t1 = *(const float4*)(trow + gx + 4);
                    }
                }
                const int u = 4 * cg;
                *(uint4*)&sRaw[0][r][u] = make_uint4(pk2(p0.x, p0.y), pk2(p0.z, p0.w),
                                                     pk2(p1.x, p1.y), pk2(p1.z, p1.w));
                *(uint4*)&sRaw[1][r][u] = make_uint4(pk2(t0.x, t0.y), pk2(t0.z, t0.w),
                                                     pk2(t1.x, t1.y), pk2(t1.z, t1.w));
            }
        }
    }
    __syncthreads();   // the only compute barrier

    // ---- per-wave: col strip ct = wv; rolling H m-tile pipeline ----
    const int co = 8 * wv;        // k-window uint base (raw px 16*ct)

    #define COMPUTE_H(mt, outf)                                                     \
    {                                                                               \
        const int rr = ((mt) == 4 && lm >= 10) ? 73 : 16 * (mt) + lm;               \
        const f16x8 aP = __builtin_bit_cast(f16x8,                                  \
            *(const uint4*)&sRaw[0][rr][co + 4 * lg]);                              \
        const f16x8 aT = __builtin_bit_cast(f16x8,                                  \
            *(const uint4*)&sRaw[1][rr][co + 4 * lg]);                              \
        f16x8 af[5];                                                                \
        af[0] = aP; af[1] = aT;                                                     \
        af[2] = aP * aP;                                                            \
        af[3] = aT * aT;                                                            \
        af[4] = aP * aT;                                                            \
        _Pragma("unroll")                                                           \
        for (int ch = 0; ch < 5; ++ch) {                                            \
            const f32x4 h = __builtin_amdgcn_mfma_f32_16x16x32_f16(af[ch], bfrag,   \
                                                                   zero4, 0, 0, 0); \
            outf[ch] = __builtin_bit_cast(f16x4,                                    \
                make_uint2(pk2(h[0], h[1]), pk2(h[2], h[3])));                      \
        }                                                                           \
    }

    f16x4 bcur[5], bnext[5];
    COMPUTE_H(0, bcur);

    float lsum = 0.f;
    #pragma unroll
    for (int rt = 0; rt < 4; ++rt) {
        COMPUTE_H(rt + 1, bnext);

        f32x4 M[5];
        #pragma unroll
        for (int ch = 0; ch < 5; ++ch) {
            const f32x4 m0 = __builtin_amdgcn_mfma_f32_16x16x16f16(a2k0, bcur[ch], zero4, 0, 0, 0);
            M[ch]          = __builtin_amdgcn_mfma_f32_16x16x16f16(a2k1, bnext[ch], m0,   0, 0, 0);
        }

        #pragma unroll
        for (int r = 0; r < 4; ++r) {
            const float mx = M[0][r], my = M[1][r];
            const float exx = M[2][r], eyy = M[3][r], exy = M[4][r];
            const float mxx = mx * mx, myy = my * my, mxy = mx * my;
            const float sx  = exx - mxx;
            const float sy  = eyy - myy;
            const float sxy = exy - mxy;
            const float num = (2.0f * mxy + 1e-4f) * (2.0f * sxy + 9e-4f);
            const float den = (mxx + myy + 1e-4f) * (sx + sy + 9e-4f);
            lsum = fmaf(num, __builtin_amdgcn_rcpf(den), lsum);
        }

        #pragma unroll
        for (int ch = 0; ch < 5; ++ch) bcur[ch] = bnext[ch];
    }
    #undef COMPUTE_H

    // ---- block reduction -> partial; last block folds the final sum ----
    #pragma unroll
    for (int off = 32; off > 0; off >>= 1)
        lsum += __shfl_down(lsum, off, 64);
    if (lane == 0) sRed[wv] = lsum;
    __syncthreads();
    if (tid == 0) {
        const float p = sRed[0] + sRed[1] + sRed[2] + sRed[3];
        // agent-scope release: visible across non-coherent XCD L2s
        __hip_atomic_store(&partial[bid], p, __ATOMIC_RELEASE, __HIP_MEMORY_SCOPE_AGENT);
        const unsigned old = __hip_atomic_fetch_add(counter, 1u, __ATOMIC_ACQ_REL,
                                                    __HIP_MEMORY_SCOPE_AGENT);
        sLast = (old == (unsigned)(nblocks - 1));
    }
    __syncthreads();

    if (sLast) {
        // fixed-order final sum (deterministic regardless of which block runs it)
        float s = 0.f;
        for (int i = tid; i < nblocks; i += NT)
            s += __hip_atomic_load(&partial[i], __ATOMIC_ACQUIRE, __HIP_MEMORY_SCOPE_AGENT);
        #pragma unroll
        for (int off = 32; off > 0; off >>= 1)
            s += __shfl_down(s, off, 64);
        if (lane == 0) sRed[wv] = s;
        __syncthreads();
        if (tid == 0)
            out[0] = 1.0f - (sRed[0] + sRed[1] + sRed[2] + sRed[3]) * inv_npix;
    }
}

extern "C" void kernel_launch(void* const* d_in, const int* in_sizes, int n_in,
                              void* d_out, int out_size, void* d_ws, size_t ws_size,
                              hipStream_t stream) {
    const float* pred   = (const float*)d_in[0];
    const float* target = (const float*)d_in[1];
    const float* kern   = (const float*)d_in[2];
    float* out      = (float*)d_out;
    float* partial  = (float*)d_ws;                              // nblocks floats
    unsigned* counter = (unsigned*)((char*)d_ws + 8192 * 4);     // after partials

    const int nimg    = in_sizes[0] / (IMG * IMG);               // 64
    const int nblocks = (IMG / BT) * (IMG / BT) * nimg;          // 4096 (mult of 8)
    const float inv_npix = 1.0f / ((float)nimg * (float)(IMG * IMG));

    hipMemsetAsync(counter, 0, sizeof(unsigned), stream);        // graph-safe
    ssim_mfma_kernel<<<dim3(nblocks), NT, 0, stream>>>(
        pred, target, kern, partial, counter, out, nblocks, inv_npix);
}

// Round 18
// 37.894 us; speedup vs baseline: 6.6459x; 6.6459x over previous
//
#include <hip/hip_runtime.h>

#define NT   256
#define IMG  512
#define BT   64     // block output tile: 64x64 (4 waves x 4 rt-quadrants)
#define RAWR 74     // staged rows: 64+10 halo; rows 74..79 have zero V-weight
#define RAWU 44     // raw row stride in uints (40 data + 4 pad)

typedef _Float16 f16x8 __attribute__((ext_vector_type(8)));
typedef _Float16 f16x4 __attribute__((ext_vector_type(4)));
typedef float    f32x4 __attribute__((ext_vector_type(4)));

__device__ inline unsigned pk2(float a, float b) {
    auto r = __builtin_amdgcn_cvt_pkrtz(a, b);     // f32x2 -> f16x2 (RTZ)
    return __builtin_bit_cast(unsigned, r);
}

// ---------------------------------------------------------------------------
// SSIM via MFMA, v12 = v10 compute (35.8 us) + in-block band build (init
// kernel deleted -> 2 dispatches). v11's fused last-block reduction REVERTED:
// its per-block agent-scope acquire/release atomics invalidate the XCD L2
// 4096x, inflating every resident block's load latency ~8x (252 us, all
// pipes <5%). Cross-XCD coherence ops are for rare sync only - never
// per-block on the hot path.
// Compute structure (verified bit-exact rounds 14-16):
//   H-conv:  H[m][16ct+n] = sum_k raw[m][16ct+k] * B1[k][n], B1[k][n]=w[k-n-3]
//   V-conv:  out[16rt+r][n] = sum_j w[j-r] * H[16rt+j][n] (two chained K=16
//            MFMAs; C-layout of K=32 MFMA == B-layout of K=16 MFMA)
//   PP/TT/PT A-frags derived in-register as products of P/T frags.
//   74 staged rows; mt=4 lm>=10 clamps to row 73 (zero V-weight, bit-exact).
// launch_bounds(256,4): round 4 showed tighter caps spill to scratch.
// ---------------------------------------------------------------------------
__global__ __launch_bounds__(NT, 4) void ssim_mfma_kernel(
    const float* __restrict__ pred,
    const float* __restrict__ target,
    const float* __restrict__ kern,
    float* __restrict__ partial)
{
    __shared__ __align__(16) unsigned sRaw[2][RAWR][RAWU];   // 25.4 KB
    __shared__ float sRed[4];

    const int tid = threadIdx.x;

    // ---- bijective XCD swizzle (gridDim.x % 8 == 0) ----
    const int bid   = blockIdx.x;
    const int chunk = (int)gridDim.x >> 3;
    const int swz   = (bid & 7) * chunk + (bid >> 3);
    const int img   = swz >> 6;               // 64 tiles per image
    const int rem   = swz & 63;
    const int tx0   = (rem & 7) * BT;
    const int ty0   = (rem >> 3) * BT;

    const int lane = tid & 63;
    const int wv   = tid >> 6;
    const int lm   = lane & 15;     // m (A row) / n (B col) / C col
    const int lg   = lane >> 4;     // k-group; C row-group

    // ---- band fragments in-block (identical arithmetic to old init kernel;
    //      ~90 cycles/block, cheaper than a serialized launch) ----
    const float invg = 1.0f / sqrtf(kern[60]);
    auto wof = [&](int i) -> float {
        return ((unsigned)i <= 10u) ? kern[55 + i] * invg : 0.0f;
    };
    unsigned bu[4], au[4];
    #pragma unroll
    for (int jp = 0; jp < 4; ++jp) {
        const int d = 8 * lg + 2 * jp - lm - 3;    // K=32 B1 band: w[k-n-3]
        bu[jp] = pk2(wof(d), wof(d + 1));
    }
    #pragma unroll
    for (int jp = 0; jp < 2; ++jp) {
        const int e = 4 * lg + 2 * jp - lm;        // K=16 A2 band: w[k-r]
        au[jp]     = pk2(wof(e),      wof(e + 1));
        au[2 + jp] = pk2(wof(e + 16), wof(e + 17));
    }
    const f16x8 bfrag = __builtin_bit_cast(f16x8, make_uint4(bu[0], bu[1], bu[2], bu[3]));
    const f16x4 a2k0  = __builtin_bit_cast(f16x4, make_uint2(au[0], au[1]));
    const f16x4 a2k1  = __builtin_bit_cast(f16x4, make_uint2(au[2], au[3]));
    const f32x4 zero4 = {0.f, 0.f, 0.f, 0.f};

    // ---- stage raw P,T (f16): 74 rows x 10 groups of 8 px ----
    {
        const float* pimg = pred   + (size_t)img * (IMG * IMG);
        const float* timg = target + (size_t)img * (IMG * IMG);
        if ((unsigned)(tx0 - 64) <= 320u && (unsigned)(ty0 - 64) <= 320u) {
            #pragma unroll
            for (int i = tid; i < RAWR * 10; i += NT) {
                const int r  = i / 10;
                const int cg = i - r * 10;
                const float* prow = pimg + (ty0 - 5 + r) * IMG + (tx0 - 8 + 8 * cg);
                const float* trow = timg + (ty0 - 5 + r) * IMG + (tx0 - 8 + 8 * cg);
                const float4 p0 = *(const float4*)(prow);
                const float4 p1 = *(const float4*)(prow + 4);
                const float4 t0 = *(const float4*)(trow);
                const float4 t1 = *(const float4*)(trow + 4);
                const int u = 4 * cg;
                *(uint4*)&sRaw[0][r][u] = make_uint4(pk2(p0.x, p0.y), pk2(p0.z, p0.w),
                                                     pk2(p1.x, p1.y), pk2(p1.z, p1.w));
                *(uint4*)&sRaw[1][r][u] = make_uint4(pk2(t0.x, t0.y), pk2(t0.z, t0.w),
                                                     pk2(t1.x, t1.y), pk2(t1.z, t1.w));
            }
        } else {
            for (int i = tid; i < RAWR * 10; i += NT) {
                const int r  = i / 10;
                const int cg = i - r * 10;
                const int gy = ty0 - 5 + r;
                const int gx = tx0 - 8 + 8 * cg;     // multiple of 4
                float4 p0 = make_float4(0.f, 0.f, 0.f, 0.f), p1 = p0, t0 = p0, t1 = p0;
                if ((unsigned)gy < IMG) {
                    const float* prow = pimg + gy * IMG;
                    const float* trow = timg + gy * IMG;
                    if ((unsigned)gx < IMG) {
                        p0 = *(const float4*)(prow + gx);
                        t0 = *(const float4*)(trow + gx);
                    }
                    if ((unsigned)(gx + 4) < IMG) {
                        p1 = *(const float4*)(prow + gx + 4);
                        t1 = *(const float4*)(trow + gx + 4);
                    }
                }
                const int u = 4 * cg;
                *(uint4*)&sRaw[0][r][u] = make_uint4(pk2(p0.x, p0.y), pk2(p0.z, p0.w),
                                                     pk2(p1.x, p1.y), pk2(p1.z, p1.w));
                *(uint4*)&sRaw[1][r][u] = make_uint4(pk2(t0.x, t0.y), pk2(t0.z, t0.w),
                                                     pk2(t1.x, t1.y), pk2(t1.z, t1.w));
            }
        }
    }
    __syncthreads();   // the only compute barrier

    // ---- per-wave: col strip ct = wv; rolling H m-tile pipeline ----
    const int co = 8 * wv;        // k-window uint base (raw px 16*ct)

    #define COMPUTE_H(mt, outf)                                                     \
    {                                                                               \
        const int rr = ((mt) == 4 && lm >= 10) ? 73 : 16 * (mt) + lm;               \
        const f16x8 aP = __builtin_bit_cast(f16x8,                                  \
            *(const uint4*)&sRaw[0][rr][co + 4 * lg]);                              \
        const f16x8 aT = __builtin_bit_cast(f16x8,                                  \
            *(const uint4*)&sRaw[1][rr][co + 4 * lg]);                              \
        f16x8 af[5];                                                                \
        af[0] = aP; af[1] = aT;                                                     \
        af[2] = aP * aP;                                                            \
        af[3] = aT * aT;                                                            \
        af[4] = aP * aT;                                                            \
        _Pragma("unroll")                                                           \
        for (int ch = 0; ch < 5; ++ch) {                                            \
            const f32x4 h = __builtin_amdgcn_mfma_f32_16x16x32_f16(af[ch], bfrag,   \
                                                                   zero4, 0, 0, 0); \
            outf[ch] = __builtin_bit_cast(f16x4,                                    \
                make_uint2(pk2(h[0], h[1]), pk2(h[2], h[3])));                      \
        }                                                                           \
    }

    f16x4 bcur[5], bnext[5];
    COMPUTE_H(0, bcur);

    float lsum = 0.f;
    #pragma unroll
    for (int rt = 0; rt < 4; ++rt) {
        COMPUTE_H(rt + 1, bnext);

        f32x4 M[5];
        #pragma unroll
        for (int ch = 0; ch < 5; ++ch) {
            const f32x4 m0 = __builtin_amdgcn_mfma_f32_16x16x16f16(a2k0, bcur[ch], zero4, 0, 0, 0);
            M[ch]          = __builtin_amdgcn_mfma_f32_16x16x16f16(a2k1, bnext[ch], m0,   0, 0, 0);
        }

        #pragma unroll
        for (int r = 0; r < 4; ++r) {
            const float mx = M[0][r], my = M[1][r];
            const float exx = M[2][r], eyy = M[3][r], exy = M[4][r];
            const float mxx = mx * mx, myy = my * my, mxy = mx * my;
            const float sx  = exx - mxx;
            const float sy  = eyy - myy;
            const float sxy = exy - mxy;
            const float num = (2.0f * mxy + 1e-4f) * (2.0f * sxy + 9e-4f);
            const float den = (mxx + myy + 1e-4f) * (sx + sy + 9e-4f);
            lsum = fmaf(num, __builtin_amdgcn_rcpf(den), lsum);
        }

        #pragma unroll
        for (int ch = 0; ch < 5; ++ch) bcur[ch] = bnext[ch];
    }
    #undef COMPUTE_H

    // ---- block reduction -> one partial per block ----
    #pragma unroll
    for (int off = 32; off > 0; off >>= 1)
        lsum += __shfl_down(lsum, off, 64);
    if (lane == 0) sRed[wv] = lsum;
    __syncthreads();
    if (tid == 0)
        partial[bid] = sRed[0] + sRed[1] + sRed[2] + sRed[3];
}

// ---------------------------------------------------------------------------
// Final reduction: sum partials, out = 1 - mean   (1 block x 1024 threads)
// ---------------------------------------------------------------------------
#define NR 1024
__global__ __launch_bounds__(NR) void ssim_reduce_kernel(
    const float* __restrict__ partial, float* __restrict__ out,
    int n, float inv_npix)
{
    __shared__ float sRed[16];
    float s = 0.0f;
    const int n4 = n >> 2;
    for (int i = threadIdx.x; i < n4; i += NR) {
        const float4 v = ((const float4*)partial)[i];
        s += (v.x + v.y) + (v.z + v.w);
    }
    for (int i = (n4 << 2) + threadIdx.x; i < n; i += NR) s += partial[i];
    #pragma unroll
    for (int off = 32; off > 0; off >>= 1)
        s += __shfl_down(s, off, 64);
    if ((threadIdx.x & 63) == 0) sRed[threadIdx.x >> 6] = s;
    __syncthreads();
    if (threadIdx.x == 0) {
        float tot = 0.0f;
        #pragma unroll
        for (int q = 0; q < 16; ++q) tot += sRed[q];
        out[0] = 1.0f - tot * inv_npix;
    }
}

extern "C" void kernel_launch(void* const* d_in, const int* in_sizes, int n_in,
                              void* d_out, int out_size, void* d_ws, size_t ws_size,
                              hipStream_t stream) {
    const float* pred   = (const float*)d_in[0];
    const float* target = (const float*)d_in[1];
    const float* kern   = (const float*)d_in[2];
    float* out     = (float*)d_out;
    float* partial = (float*)d_ws;                          // nblocks floats

    const int nimg    = in_sizes[0] / (IMG * IMG);          // 64
    const int nblocks = (IMG / BT) * (IMG / BT) * nimg;     // 4096 (mult of 8)
    const float inv_npix = 1.0f / ((float)nimg * (float)(IMG * IMG));

    ssim_mfma_kernel<<<dim3(nblocks), NT, 0, stream>>>(pred, target, kern, partial);
    ssim_reduce_kernel<<<1, NR, 0, stream>>>(partial, out, nblocks, inv_npix);
}

// Round 19
// 36.306 us; speedup vs baseline: 6.9366x; 1.0437x over previous
//
#include <hip/hip_runtime.h>

#define NT   256
#define IMG  512
#define BT   64     // block output tile: 64x64 (4 waves x 4 rt-quadrants)
#define RAWR 74     // staged rows: 64+10 halo; rows 74..79 have zero V-weight
#define RAWU 44     // raw row stride in uints (40 data + 4 pad)
#define WS_PARTIAL_OFF 1024   // floats; band table occupies first 4KB of ws

typedef _Float16 f16x8 __attribute__((ext_vector_type(8)));
typedef _Float16 f16x4 __attribute__((ext_vector_type(4)));
typedef float    f32x4 __attribute__((ext_vector_type(4)));

__device__ inline unsigned pk2(float a, float b) {
    auto r = __builtin_amdgcn_cvt_pkrtz(a, b);     // f32x2 -> f16x2 (RTZ)
    return __builtin_bit_cast(unsigned, r);
}

// ---------------------------------------------------------------------------
// One-time init: per-lane band fragments -> ws. (Kept as a separate kernel:
// round 18 showed in-block rebuild costs ~2 us - the 17 kern loads + ~90 VALU
// sit on every block's critical path before staging can issue.)
//   tab[l*16+0..3] : B1 frag, K=32 h-conv B operand, B1[k][n]=w[k-n-3]
//   tab[l*16+4..5] : A2 k-tile 0 (K=16 v-conv A), A2[r][k]=w[k-r]
//   tab[l*16+6..7] : A2 k-tile 1,                  w[k+16-r]
// ---------------------------------------------------------------------------
__global__ void ssim_init_kernel(const float* __restrict__ kern,
                                 unsigned* __restrict__ tab) {
    const int l  = threadIdx.x;        // 0..63
    const int lm = l & 15;
    const int lg = l >> 4;
    const float invg = 1.0f / sqrtf(kern[60]);
    auto wof = [&](int i) -> float {
        return ((unsigned)i <= 10u) ? kern[55 + i] * invg : 0.0f;
    };
    unsigned bu[4], au[4];
    #pragma unroll
    for (int jp = 0; jp < 4; ++jp) {
        const int d = 8 * lg + 2 * jp - lm - 3;
        bu[jp] = pk2(wof(d), wof(d + 1));
    }
    #pragma unroll
    for (int jp = 0; jp < 2; ++jp) {
        const int e = 4 * lg + 2 * jp - lm;
        au[jp]     = pk2(wof(e),      wof(e + 1));
        au[2 + jp] = pk2(wof(e + 16), wof(e + 17));
    }
    *(uint4*)&tab[l * 16]     = make_uint4(bu[0], bu[1], bu[2], bu[3]);
    *(uint4*)&tab[l * 16 + 4] = make_uint4(au[0], au[1], au[2], au[3]);
}

// ---------------------------------------------------------------------------
// SSIM via MFMA, v13 = v10 (proven 35.8 us) + T5 s_setprio(1) around the
// per-wave compute chain. Mechanism: 6 independent blocks/CU are at different
// phases (staging vs compute); prioritizing compute-phase waves lets their
// dependent H->V MFMA chains drain instead of round-robining with staging
// waves' VALU bursts (the m191 "independent blocks" case where setprio pays).
// REVERTED experiments: v5 direct-global frags (-37%), v6 T14 2-tile (-33%),
// v7 T2 swizzle (-20%), v11 fused atomic reduce (-7x: agent-scope atomics
// poison XCD L2), v12 in-block band build (-6%).
// Compute structure (verified bit-exact rounds 14-18):
//   H-conv:  H[m][16ct+n] = sum_k raw[m][16ct+k] * B1[k][n], B1[k][n]=w[k-n-3]
//   V-conv:  out[16rt+r][n] = sum_j w[j-r] * H[16rt+j][n] (two chained K=16
//            MFMAs; C-layout of K=32 MFMA == B-layout of K=16 MFMA)
//   PP/TT/PT A-frags derived in-register as products of P/T frags.
//   74 staged rows; mt=4 lm>=10 clamps to row 73 (zero V-weight, bit-exact).
// launch_bounds(256,4): round 4 showed tighter caps spill to scratch.
// ---------------------------------------------------------------------------
__global__ __launch_bounds__(NT, 4) void ssim_mfma_kernel(
    const float* __restrict__ pred,
    const float* __restrict__ target,
    const unsigned* __restrict__ tab,
    float* __restrict__ partial)
{
    __shared__ __align__(16) unsigned sRaw[2][RAWR][RAWU];   // 25.4 KB
    __shared__ float sRed[4];

    const int tid = threadIdx.x;

    // ---- bijective XCD swizzle (gridDim.x % 8 == 0) ----
    const int bid   = blockIdx.x;
    const int chunk = (int)gridDim.x >> 3;
    const int swz   = (bid & 7) * chunk + (bid >> 3);
    const int img   = swz >> 6;               // 64 tiles per image
    const int rem   = swz & 63;
    const int tx0   = (rem & 7) * BT;
    const int ty0   = (rem >> 3) * BT;

    const int lane = tid & 63;
    const int wv   = tid >> 6;
    const int lm   = lane & 15;     // m (A row) / n (B col) / C col
    const int lg   = lane >> 4;     // k-group; C row-group

    // ---- band fragments: two L2-hit vector loads ----
    const uint4 bq = *(const uint4*)&tab[lane * 16];
    const uint4 aq = *(const uint4*)&tab[lane * 16 + 4];
    const f16x8 bfrag = __builtin_bit_cast(f16x8, bq);
    const f16x4 a2k0  = __builtin_bit_cast(f16x4, make_uint2(aq.x, aq.y));
    const f16x4 a2k1  = __builtin_bit_cast(f16x4, make_uint2(aq.z, aq.w));
    const f32x4 zero4 = {0.f, 0.f, 0.f, 0.f};

    // ---- stage raw P,T (f16): 74 rows x 10 groups of 8 px ----
    {
        const float* pimg = pred   + (size_t)img * (IMG * IMG);
        const float* timg = target + (size_t)img * (IMG * IMG);
        if ((unsigned)(tx0 - 64) <= 320u && (unsigned)(ty0 - 64) <= 320u) {
            #pragma unroll
            for (int i = tid; i < RAWR * 10; i += NT) {
                const int r  = i / 10;
                const int cg = i - r * 10;
                const float* prow = pimg + (ty0 - 5 + r) * IMG + (tx0 - 8 + 8 * cg);
                const float* trow = timg + (ty0 - 5 + r) * IMG + (tx0 - 8 + 8 * cg);
                const float4 p0 = *(const float4*)(prow);
                const float4 p1 = *(const float4*)(prow + 4);
                const float4 t0 = *(const float4*)(trow);
                const float4 t1 = *(const float4*)(trow + 4);
                const int u = 4 * cg;
                *(uint4*)&sRaw[0][r][u] = make_uint4(pk2(p0.x, p0.y), pk2(p0.z, p0.w),
                                                     pk2(p1.x, p1.y), pk2(p1.z, p1.w));
                *(uint4*)&sRaw[1][r][u] = make_uint4(pk2(t0.x, t0.y), pk2(t0.z, t0.w),
                                                     pk2(t1.x, t1.y), pk2(t1.z, t1.w));
            }
        } else {
            for (int i = tid; i < RAWR * 10; i += NT) {
                const int r  = i / 10;
                const int cg = i - r * 10;
                const int gy = ty0 - 5 + r;
                const int gx = tx0 - 8 + 8 * cg;     // multiple of 4
                float4 p0 = make_float4(0.f, 0.f, 0.f, 0.f), p1 = p0, t0 = p0, t1 = p0;
                if ((unsigned)gy < IMG) {
                    const float* prow = pimg + gy * IMG;
                    const float* trow = timg + gy * IMG;
                    if ((unsigned)gx < IMG) {
                        p0 = *(const float4*)(prow + gx);
                        t0 = *(const float4*)(trow + gx);
                    }
                    if ((unsigned)(gx + 4) < IMG) {
                        p1 = *(const float4*)(prow + gx + 4);
                        t1 = *(const float4*)(trow + gx + 4);
                    }
                }
                const int u = 4 * cg;
                *(uint4*)&sRaw[0][r][u] = make_uint4(pk2(p0.x, p0.y), pk2(p0.z, p0.w),
                                                     pk2(p1.x, p1.y), pk2(p1.z, p1.w));
                *(uint4*)&sRaw[1][r][u] = make_uint4(pk2(t0.x, t0.y), pk2(t0.z, t0.w),
                                                     pk2(t1.x, t1.y), pk2(t1.z, t1.w));
            }
        }
    }
    __syncthreads();   // the only compute barrier

    // ---- per-wave: col strip ct = wv; rolling H m-tile pipeline ----
    const int co = 8 * wv;        // k-window uint base (raw px 16*ct)

    #define COMPUTE_H(mt, outf)                                                     \
    {                                                                               \
        const int rr = ((mt) == 4 && lm >= 10) ? 73 : 16 * (mt) + lm;               \
        const f16x8 aP = __builtin_bit_cast(f16x8,                                  \
            *(const uint4*)&sRaw[0][rr][co + 4 * lg]);                              \
        const f16x8 aT = __builtin_bit_cast(f16x8,                                  \
            *(const uint4*)&sRaw[1][rr][co + 4 * lg]);                              \
        f16x8 af[5];                                                                \
        af[0] = aP; af[1] = aT;                                                     \
        af[2] = aP * aP;                                                            \
        af[3] = aT * aT;                                                            \
        af[4] = aP * aT;                                                            \
        _Pragma("unroll")                                                           \
        for (int ch = 0; ch < 5; ++ch) {                                            \
            const f32x4 h = __builtin_amdgcn_mfma_f32_16x16x32_f16(af[ch], bfrag,   \
                                                                   zero4, 0, 0, 0); \
            outf[ch] = __builtin_bit_cast(f16x4,                                    \
                make_uint2(pk2(h[0], h[1]), pk2(h[2], h[3])));                      \
        }                                                                           \
    }

    __builtin_amdgcn_s_setprio(1);      // T5: favor compute-phase waves

    f16x4 bcur[5], bnext[5];
    COMPUTE_H(0, bcur);

    float lsum = 0.f;
    #pragma unroll
    for (int rt = 0; rt < 4; ++rt) {
        COMPUTE_H(rt + 1, bnext);

        f32x4 M[5];
        #pragma unroll
        for (int ch = 0; ch < 5; ++ch) {
            const f32x4 m0 = __builtin_amdgcn_mfma_f32_16x16x16f16(a2k0, bcur[ch], zero4, 0, 0, 0);
            M[ch]          = __builtin_amdgcn_mfma_f32_16x16x16f16(a2k1, bnext[ch], m0,   0, 0, 0);
        }

        #pragma unroll
        for (int r = 0; r < 4; ++r) {
            const float mx = M[0][r], my = M[1][r];
            const float exx = M[2][r], eyy = M[3][r], exy = M[4][r];
            const float mxx = mx * mx, myy = my * my, mxy = mx * my;
            const float sx  = exx - mxx;
            const float sy  = eyy - myy;
            const float sxy = exy - mxy;
            const float num = (2.0f * mxy + 1e-4f) * (2.0f * sxy + 9e-4f);
            const float den = (mxx + myy + 1e-4f) * (sx + sy + 9e-4f);
            lsum = fmaf(num, __builtin_amdgcn_rcpf(den), lsum);
        }

        #pragma unroll
        for (int ch = 0; ch < 5; ++ch) bcur[ch] = bnext[ch];
    }
    #undef COMPUTE_H

    __builtin_amdgcn_s_setprio(0);

    // ---- block reduction -> one partial per block ----
    #pragma unroll
    for (int off = 32; off > 0; off >>= 1)
        lsum += __shfl_down(lsum, off, 64);
    if (lane == 0) sRed[wv] = lsum;
    __syncthreads();
    if (tid == 0)
        partial[bid] = sRed[0] + sRed[1] + sRed[2] + sRed[3];
}

// ---------------------------------------------------------------------------
// Final reduction: sum partials, out = 1 - mean   (1 block x 1024 threads)
// ---------------------------------------------------------------------------
#define NR 1024
__global__ __launch_bounds__(NR) void ssim_reduce_kernel(
    const float* __restrict__ partial, float* __restrict__ out,
    int n, float inv_npix)
{
    __shared__ float sRed[16];
    float s = 0.0f;
    const int n4 = n >> 2;
    for (int i = threadIdx.x; i < n4; i += NR) {
        const float4 v = ((const float4*)partial)[i];
        s += (v.x + v.y) + (v.z + v.w);
    }
    for (int i = (n4 << 2) + threadIdx.x; i < n; i += NR) s += partial[i];
    #pragma unroll
    for (int off = 32; off > 0; off >>= 1)
        s += __shfl_down(s, off, 64);
    if ((threadIdx.x & 63) == 0) sRed[threadIdx.x >> 6] = s;
    __syncthreads();
    if (threadIdx.x == 0) {
        float tot = 0.0f;
        #pragma unroll
        for (int q = 0; q < 16; ++q) tot += sRed[q];
        out[0] = 1.0f - tot * inv_npix;
    }
}

extern "C" void kernel_launch(void* const* d_in, const int* in_sizes, int n_in,
                              void* d_out, int out_size, void* d_ws, size_t ws_size,
                              hipStream_t stream) {
    const float* pred   = (const float*)d_in[0];
    const float* target = (const float*)d_in[1];
    const float* kern   = (const float*)d_in[2];
    float* out     = (float*)d_out;
    unsigned* tab  = (unsigned*)d_ws;                       // 4 KB band table
    float* partial = (float*)d_ws + WS_PARTIAL_OFF;         // per-block sums

    const int nimg    = in_sizes[0] / (IMG * IMG);          // 64
    const int nblocks = (IMG / BT) * (IMG / BT) * nimg;     // 4096 (mult of 8)
    const float inv_npix = 1.0f / ((float)nimg * (float)(IMG * IMG));

    ssim_init_kernel<<<1, 64, 0, stream>>>(kern, tab);
    ssim_mfma_kernel<<<dim3(nblocks), NT, 0, stream>>>(pred, target, tab, partial);
    ssim_reduce_kernel<<<1, NR, 0, stream>>>(partial, out, nblocks, inv_npix);
}